// Round 2
// baseline (532.904 us; speedup 1.0000x reference)
//
#include <hip/hip_runtime.h>

#define TB 128  // 2 waves: wave0 = forward, wave1 = backward

__device__ __forceinline__ float fast_sigmoid(float x) {
  float e = __expf(-x);
  return __builtin_amdgcn_rcpf(1.f + e);
}
__device__ __forceinline__ float fast_tanh(float x) {
  float e = __expf(-2.f * x);
  return fmaf(2.f, __builtin_amdgcn_rcpf(1.f + e), -1.f);
}

// Generic scan: lane g (< 4H) computes gate g; lanes j < H keep c_j, write h.
// in_buf: [T][INS] (first D used). POOL: write pair-max at [(t/2)][OUTS].
// TOUT: write transposed out_buf[(wave*H+lane)*T + t] (final layer -> d_out).
template<int D, int H, int T, int INS, int OUTS, bool POOL, bool TOUT>
__device__ __forceinline__ void lstm_scan(const float* __restrict__ wih,
                                          const float* __restrict__ whh,
                                          const float* __restrict__ bias,
                                          const float* in_buf,
                                          float* out_buf,
                                          int wave, int lane,
                                          float* h_lds, float* g_lds) {
  constexpr int G = 4 * H;
  float wr[D], hr[H], bb = 0.f;
#pragma unroll
  for (int i = 0; i < D; ++i) wr[i] = 0.f;
#pragma unroll
  for (int i = 0; i < H; ++i) hr[i] = 0.f;
  if (lane < G) {
    const float* p = wih + lane * D;
#pragma unroll
    for (int i = 0; i < D; i += 4) {
      float4 v = *(const float4*)(p + i);
      wr[i] = v.x; wr[i + 1] = v.y; wr[i + 2] = v.z; wr[i + 3] = v.w;
    }
    const float* q = whh + lane * H;
#pragma unroll
    for (int i = 0; i < H; ++i) hr[i] = q[i];
    bb = bias[lane];
  }
  if (lane < H) h_lds[lane] = 0.f;
  __builtin_amdgcn_wave_barrier();
  float cs = 0.f, pm = 0.f;
  int t = wave ? (T - 1) : 0;
  const int dt = wave ? -1 : 1;
  float cur[D];
#pragma unroll
  for (int i = 0; i < D; i += 4)
    *(float4*)(cur + i) = *(const float4*)(in_buf + t * INS + i);

  for (int s = 0; s < T; ++s) {
    // input-side dot (off the h critical path)
    float acc = bb;
#pragma unroll
    for (int i = 0; i < D; ++i) acc = fmaf(wr[i], cur[i], acc);
    // prefetch next step's input vector
    int tn = t + dt;
    if (s + 1 < T) {
#pragma unroll
      for (int i = 0; i < D; i += 4)
        *(float4*)(cur + i) = *(const float4*)(in_buf + tn * INS + i);
    }
    // recurrent dot: broadcast h from per-wave LDS
#pragma unroll
    for (int i = 0; i < H; i += 4) {
      float4 h4 = *(const float4*)(h_lds + i);
      acc = fmaf(hr[i + 0], h4.x, acc);
      acc = fmaf(hr[i + 1], h4.y, acc);
      acc = fmaf(hr[i + 2], h4.z, acc);
      acc = fmaf(hr[i + 3], h4.w, acc);
    }
    // i,f,o -> sigmoid; g -> tanh = 2*sigmoid(2x)-1
    const bool isg = (lane >= 2 * H) && (lane < 3 * H);
    float u = isg ? 2.f * acc : acc;
    float sg = fast_sigmoid(u);
    float a = isg ? fmaf(2.f, sg, -1.f) : sg;
    g_lds[lane] = a;
    __builtin_amdgcn_wave_barrier();
    if (lane < H) {
      float ig = g_lds[lane];
      float fg = g_lds[lane + H];
      float gg = g_lds[lane + 2 * H];
      float og = g_lds[lane + 3 * H];
      cs = fmaf(fg, cs, ig * gg);
      float hv = og * fast_tanh(cs);
      h_lds[lane] = hv;
      if (TOUT) {
        out_buf[(wave * H + lane) * T + t] = hv;
      } else if (POOL) {
        // both directions visit a time-pair in consecutive steps
        if (s & 1) out_buf[(t >> 1) * OUTS + wave * H + lane] = fmaxf(pm, hv);
        else pm = hv;
      } else {
        out_buf[t * OUTS + wave * H + lane] = hv;
      }
    }
    __builtin_amdgcn_wave_barrier();
    t = tn;
  }
}

// L1a: conv+BN+input-GEMM folded to 11 effective inputs; x staged in LDS.
template<int T>
__device__ __forceinline__ void lstm_scan_l1a(const float* weff, float beff,
                                              const float* hrw,
                                              const float (*xs)[12],
                                              float* __restrict__ out_buf,
                                              int wave, int lane,
                                              float* h_lds, float* g_lds) {
  if (lane < 16) h_lds[lane] = 0.f;
  __builtin_amdgcn_wave_barrier();
  float cs = 0.f;
  int t = wave ? (T - 1) : 0;
  const int dt = wave ? -1 : 1;
  for (int s = 0; s < T; ++s) {
    float4 x0 = *(const float4*)&xs[t][0];
    float4 x1 = *(const float4*)&xs[t][4];
    float4 x2 = *(const float4*)&xs[t][8];
    float acc = beff;
    acc = fmaf(weff[0], x0.x, acc);
    acc = fmaf(weff[1], x0.y, acc);
    acc = fmaf(weff[2], x0.z, acc);
    acc = fmaf(weff[3], x0.w, acc);
    acc = fmaf(weff[4], x1.x, acc);
    acc = fmaf(weff[5], x1.y, acc);
    acc = fmaf(weff[6], x1.z, acc);
    acc = fmaf(weff[7], x1.w, acc);
    acc = fmaf(weff[8], x2.x, acc);
    acc = fmaf(weff[9], x2.y, acc);
    acc = fmaf(weff[10], x2.z, acc);
#pragma unroll
    for (int i = 0; i < 16; i += 4) {
      float4 h4 = *(const float4*)(h_lds + i);
      acc = fmaf(hrw[i + 0], h4.x, acc);
      acc = fmaf(hrw[i + 1], h4.y, acc);
      acc = fmaf(hrw[i + 2], h4.z, acc);
      acc = fmaf(hrw[i + 3], h4.w, acc);
    }
    const bool isg = (lane >= 32) && (lane < 48);
    float u = isg ? 2.f * acc : acc;
    float sg = fast_sigmoid(u);
    float a = isg ? fmaf(2.f, sg, -1.f) : sg;
    g_lds[lane] = a;
    __builtin_amdgcn_wave_barrier();
    if (lane < 16) {
      float ig = g_lds[lane];
      float fg = g_lds[lane + 16];
      float gg = g_lds[lane + 32];
      float og = g_lds[lane + 48];
      cs = fmaf(fg, cs, ig * gg);
      float hv = og * fast_tanh(cs);
      h_lds[lane] = hv;
      out_buf[t * 32 + wave * 16 + lane] = hv;
    }
    __builtin_amdgcn_wave_barrier();
    t += dt;
  }
}

__global__ __launch_bounds__(TB) void lstm_all(
    const float* __restrict__ x,
    const float* __restrict__ conv_w, const float* __restrict__ conv_b,
    const float* __restrict__ bn_g, const float* __restrict__ bn_b,
    const float* __restrict__ bn_m, const float* __restrict__ bn_v,
    const float* __restrict__ w1a_ih, const float* __restrict__ w1a_hh, const float* __restrict__ b1a,
    const float* __restrict__ w1b_ih, const float* __restrict__ w1b_hh, const float* __restrict__ b1b,
    const float* __restrict__ w2a_ih, const float* __restrict__ w2a_hh, const float* __restrict__ b2a,
    const float* __restrict__ w2b_ih, const float* __restrict__ w2b_hh, const float* __restrict__ b2b,
    const float* __restrict__ w3_ih, const float* __restrict__ w3_hh, const float* __restrict__ b3,
    float* __restrict__ out, float* __restrict__ ws, int row0) {
  const int row = row0 + blockIdx.x;
  const int tid = threadIdx.x;
  const int wave = tid >> 6;
  const int lane = tid & 63;

  // L: reused LDS region. Phase1: xs[512][12] (6144 f). Phase2: l1b pooled
  // out [256][32] (8192 f). Phase3: l2b pooled out [128][16] (2048 f).
  __shared__ __align__(16) float L[8192];
  __shared__ __align__(16) float w2c[64][11];  // conv_w * inv (BN folded)
  __shared__ float b2c[64];
  __shared__ __align__(16) float h_lds[2][16];
  __shared__ __align__(16) float g_lds[2][64];

  // per-block ws slice (indexed by blockIdx.x so chunked launches reuse ws)
  float* A = ws + (size_t)blockIdx.x * 16384;  // 64 KiB per row

  // stage x[row] (11x512) transposed into LDS
  float (*xs)[12] = (float(*)[12])L;
  const float* xrow = x + (size_t)row * 5632;
  for (int i = tid; i < 5632; i += TB) {
    int c = i >> 9;
    int t = i & 511;
    xs[t][c] = xrow[i];
  }
  // fold BN into conv
  if (tid < 64) {
    float inv = bn_g[tid] * rsqrtf(bn_v[tid] + 1e-5f);
    for (int c = 0; c < 11; ++c) w2c[tid][c] = conv_w[tid * 11 + c] * inv;
    b2c[tid] = fmaf(conv_b[tid] - bn_m[tid], inv, bn_b[tid]);
  }
  __syncthreads();

  // fold conv+BN into L1a input weights: Weff[g][c] = sum_d wih[g][d]*w2c[d][c]
  float weff[11];
  float beff;
  {
#pragma unroll
    for (int c = 0; c < 11; ++c) weff[c] = 0.f;
    const float* wih = w1a_ih + wave * 4096 + lane * 64;
    beff = b1a[wave * 64 + lane];
    for (int d = 0; d < 64; ++d) {
      float wd = wih[d];
      beff = fmaf(wd, b2c[d], beff);
#pragma unroll
      for (int c = 0; c < 11; ++c) weff[c] = fmaf(wd, w2c[d][c], weff[c]);
    }
  }
  float hrw[16];
  {
    const float* q = w1a_hh + wave * 1024 + lane * 16;
#pragma unroll
    for (int i = 0; i < 16; ++i) hrw[i] = q[i];
  }
  // L1a: xs (LDS) -> A [512][32]
  lstm_scan_l1a<512>(weff, beff, hrw, xs, A, wave, lane, h_lds[wave], g_lds[wave]);
  __syncthreads();

  // L1b + pool: A [512][32] -> L [256][32]
  lstm_scan<32, 16, 512, 32, 32, true, false>(
      w1b_ih + wave * 2048, w1b_hh + wave * 1024, b1b + wave * 64,
      A, L, wave, lane, h_lds[wave], g_lds[wave]);
  __syncthreads();

  // L2a: L [256][32] -> A [256][16]
  lstm_scan<32, 8, 256, 32, 16, false, false>(
      w2a_ih + wave * 1024, w2a_hh + wave * 256, b2a + wave * 32,
      L, A, wave, lane, h_lds[wave], g_lds[wave]);
  __syncthreads();

  // L2b + pool: A [256][16] -> L [128][16]
  lstm_scan<16, 8, 256, 16, 16, true, false>(
      w2b_ih + wave * 512, w2b_hh + wave * 256, b2b + wave * 32,
      A, L, wave, lane, h_lds[wave], g_lds[wave]);
  __syncthreads();

  // L3: L [128][16] -> out[row][ch][t] directly (transposed store)
  lstm_scan<16, 4, 128, 16, 8, false, true>(
      w3_ih + wave * 256, w3_hh + wave * 64, b3 + wave * 16,
      L, out + (size_t)row * 1024, wave, lane, h_lds[wave], g_lds[wave]);
}

extern "C" void kernel_launch(void* const* d_in, const int* in_sizes, int n_in,
                              void* d_out, int out_size, void* d_ws, size_t ws_size,
                              hipStream_t stream) {
  const float* x      = (const float*)d_in[0];
  const float* conv_w = (const float*)d_in[1];
  const float* conv_b = (const float*)d_in[2];
  const float* bn_g   = (const float*)d_in[3];
  const float* bn_b   = (const float*)d_in[4];
  const float* bn_m   = (const float*)d_in[5];
  const float* bn_v   = (const float*)d_in[6];
  const float* w1a_ih = (const float*)d_in[7];
  const float* w1a_hh = (const float*)d_in[8];
  const float* b1a    = (const float*)d_in[9];
  const float* w1b_ih = (const float*)d_in[10];
  const float* w1b_hh = (const float*)d_in[11];
  const float* b1b    = (const float*)d_in[12];
  const float* w2a_ih = (const float*)d_in[13];
  const float* w2a_hh = (const float*)d_in[14];
  const float* b2a    = (const float*)d_in[15];
  const float* w2b_ih = (const float*)d_in[16];
  const float* w2b_hh = (const float*)d_in[17];
  const float* b2b    = (const float*)d_in[18];
  const float* w3_ih  = (const float*)d_in[19];
  const float* w3_hh  = (const float*)d_in[20];
  const float* b3     = (const float*)d_in[21];

  const size_t per_row_bytes = 16384 * sizeof(float);  // 64 KiB
  int rows_per = (int)(ws_size / per_row_bytes);
  if (rows_per < 1) rows_per = 1;
  if (rows_per > 1024) rows_per = 1024;

  for (int r0 = 0; r0 < 1024; r0 += rows_per) {
    int n = 1024 - r0;
    if (n > rows_per) n = rows_per;
    lstm_all<<<n, TB, 0, stream>>>(x, conv_w, conv_b, bn_g, bn_b, bn_m, bn_v,
                                   w1a_ih, w1a_hh, b1a, w1b_ih, w1b_hh, b1b,
                                   w2a_ih, w2a_hh, b2a, w2b_ih, w2b_hh, b2b,
                                   w3_ih, w3_hh, b3,
                                   (float*)d_out, (float*)d_ws, r0);
  }
}